// Round 1
// baseline (96617.676 us; speedup 1.0000x reference)
//
#include <hip/hip_runtime.h>
#include <hip/hip_bf16.h>
#include <stdint.h>

#define AG __HIP_MEMORY_SCOPE_AGENT
#define GMAIN 128
#define GTOT  136   // 128 main blocks + 8 attention blocks

// ---------------- workspace layout (bytes) ----------------
static constexpr size_t OFF_WA  = 0;                               // [2][128][18][32][8][8] bf16  (Wih_att|Whh_att, K=1152 pad)
static constexpr size_t SZ_WA   = (size_t)2*4096*1152*2;
static constexpr size_t OFF_W1  = OFF_WA + SZ_WA;                  // [2][128][34][32][8][8] bf16  ([ha|h1prev|ctx], K=2176)
static constexpr size_t SZ_W1   = (size_t)2*4096*2176*2;
static constexpr size_t OFF_W2  = OFF_W1 + SZ_W1;                  // [2][128][32][32][8][8] bf16  ([h1|h2prev], K=2048)
static constexpr size_t SZ_W2   = (size_t)2*4096*2048*2;
static constexpr size_t OFF_WD  = OFF_W2 + SZ_W2;                  // [2][128][4][8][32][8] bf16   (Wd^T)
static constexpr size_t SZ_WD   = (size_t)2*1024*1024*2;
static constexpr size_t OFF_WO  = OFF_WD + SZ_WD;                  // [2][80][2][128][8] bf16      (Wo^T)
static constexpr size_t SZ_WO   = (size_t)2*160*1024*2;
static constexpr size_t OFF_WQK = OFF_WO + SZ_WO;                  // [2][8][16][24][8][8] bf16    (inv * Wq@keys^T)
static constexpr size_t SZ_WQK  = (size_t)2*192*1024*2;
static constexpr size_t OFF_VAL = OFF_WQK + SZ_WQK;                // [2][4][3][32][8][8] bf16     (vals^T)
static constexpr size_t SZ_VAL  = (size_t)2*128*192*2;
static constexpr size_t OFF_KEY = OFF_VAL + SZ_VAL;                // [2][192][128] f32
static constexpr size_t SZ_KEY  = (size_t)2*192*128*4;
static constexpr size_t OFF_ENC = OFF_KEY + SZ_KEY;                // [192][640] f32
static constexpr size_t SZ_ENC  = (size_t)192*640*4;
static constexpr size_t OFF_RB  = OFF_ENC + SZ_ENC;                // residual^T [512][80] f32
static constexpr size_t SZ_RB   = (size_t)512*80*4;
static constexpr size_t OFF_SEQ = OFF_RB + SZ_RB;                  // intermediate seq [512][80] f32
static constexpr size_t SZ_SEQ  = (size_t)512*80*4;
static constexpr size_t OFF_VA  = OFF_SEQ + SZ_SEQ;                // [2][1152] f32: [y(80) | ha(1024) | pad]
static constexpr size_t OFF_V1  = OFF_VA + (size_t)2*1152*4;       // [2][2176] f32: [ha | h1prev | ctx]
static constexpr size_t OFF_V2  = OFF_V1 + (size_t)2*2176*4;       // [2][2048] f32: [h1 | h2prev]
static constexpr size_t OFF_HD  = OFF_V2 + (size_t)2*2048*4;       // [1024] f32
static constexpr size_t OFF_SL  = OFF_HD + (size_t)1024*4;         // barrier slots (256 ints)
static constexpr size_t OFF_FLG = OFF_SL + 1024;                   // ctx-ready flag
static constexpr size_t OFF_SC  = OFF_FLG + 256;                   // scorebuf [192] f32
static constexpr size_t OFF_ASL = OFF_SC + 1024;                   // attention mini-slots [8]
static constexpr size_t NEEDED  = OFF_ASL + 256;

// ---------------- device helpers ----------------
__device__ __forceinline__ float aldx(const float* p){ return __hip_atomic_load(p, __ATOMIC_RELAXED, AG); }
__device__ __forceinline__ void  astx(float* p, float v){ __hip_atomic_store(p, v, __ATOMIC_RELAXED, AG); }
__device__ __forceinline__ unsigned long long aldx8(const unsigned long long* p){ return __hip_atomic_load(p, __ATOMIC_RELAXED, AG); }

__device__ __forceinline__ float dot8(uint4 w, const float* v){
  float4 a = *(const float4*)v;
  float4 b = *(const float4*)(v+4);
  float s;
  s = __uint_as_float(w.x << 16) * a.x;
  s = fmaf(__uint_as_float(w.x & 0xffff0000u), a.y, s);
  s = fmaf(__uint_as_float(w.y << 16),         a.z, s);
  s = fmaf(__uint_as_float(w.y & 0xffff0000u), a.w, s);
  s = fmaf(__uint_as_float(w.z << 16),         b.x, s);
  s = fmaf(__uint_as_float(w.z & 0xffff0000u), b.y, s);
  s = fmaf(__uint_as_float(w.w << 16),         b.z, s);
  s = fmaf(__uint_as_float(w.w & 0xffff0000u), b.w, s);
  return s;
}
__device__ __forceinline__ float sigf(float x){ return 1.f/(1.f+__expf(-x)); }
__device__ __forceinline__ float tanhf_(float x){
  x = fminf(12.f, fmaxf(-12.f, x));
  float t = __expf(2.f*x);
  return (t-1.f)/(t+1.f);
}

// ---------------- prep kernels ----------------
__global__ void k_init(float* z, int n){ int i = blockIdx.x*256 + threadIdx.x; if (i<n) z[i]=0.f; }

__global__ void k_rbuf(const float* res, float* rb){
  int i = blockIdx.x*256 + threadIdx.x; if (i >= 512*80) return;
  int t = i/80, m = i - t*80;
  rb[i] = res[m*512 + t];
}

__global__ void k_enc(const float* emb, const float* spk, const int* text, float* enc){
  int i = blockIdx.x*256 + threadIdx.x; if (i >= 192*640) return;
  int s = i/640, e = i - s*640;
  enc[i] = (e < 512) ? emb[(size_t)text[s]*512 + e] : spk[e-512];
}

__global__ void k_keysvals(const float* enc, const float* Wk, const float* Wv,
                           float* keys, __hip_bfloat16* valsT){
  int i = blockIdx.x*256 + threadIdx.x; if (i >= 2*192*128) return;
  int f = i/(192*128); int r = i - f*192*128; int s = r/128, a = r - s*128;
  float ka=0.f, va=0.f;
  for (int e=0;e<640;++e){
    float x = enc[s*640+e];
    ka = fmaf(x, Wk[((size_t)f*640+e)*128+a], ka);
    va = fmaf(x, Wv[((size_t)f*640+e)*128+a], va);
  }
  keys[((size_t)f*192+s)*128+a] = ka;
  size_t d = ((((size_t)(f*4 + (a>>5))*3 + (s>>6))*32 + (a&31))*8 + ((s>>3)&7))*8 + (s&7);
  valsT[d] = __float2bfloat16(va);
}

__global__ void k_wqk(const float* Wq, const float* keys, __hip_bfloat16* dst){
  int i = blockIdx.x*256 + threadIdx.x; if (i >= 2*192*1024) return;
  int f = i/(192*1024); int r = i - f*192*1024; int s = r/1024, h = r - s*1024;
  float acc=0.f;
  for (int a=0;a<128;++a)
    acc = fmaf(Wq[((size_t)f*1024+h)*128+a], keys[((size_t)f*192+s)*128+a], acc);
  acc *= 0.08838834764831845f; // 1/sqrt(128)
  int ab = s/24, rl = s - ab*24;
  size_t d = ((((size_t)(f*8 + ab)*16 + (h>>6))*192 + rl*8 + ((h>>3)&7)))*8 + (h&7);
  dst[d] = __float2bfloat16(acc);
}

__global__ void k_packA(const float* Wih, const float* Whh, __hip_bfloat16* dst){
  int c = blockIdx.x*256 + threadIdx.x; if (c >= 2*589824) return;
  int f = c / 589824; int r = c - f*589824;
  int b = r / 4608; r -= b*4608;
  int j = r / 256;  r -= j*256;
  int rs = r >> 3, ks = r & 7;
  int row = (rs>>3)*1024 + b*8 + (rs&7);
  int k0 = j*64 + ks*8;
  __hip_bfloat16* o = dst + (size_t)c*8;
  for (int e=0;e<8;++e){
    int k = k0+e; float v;
    if (k < 80)        v = Wih[((size_t)f*4096+row)*80 + k];
    else if (k < 1104) v = Whh[((size_t)f*4096+row)*1024 + (k-80)];
    else               v = 0.f;
    o[e] = __float2bfloat16(v);
  }
}

__global__ void k_pack1(const float* Wih1, const float* Whh1, __hip_bfloat16* dst){
  int c = blockIdx.x*256 + threadIdx.x; if (c >= 2*1114112) return;
  int f = c / 1114112; int r = c - f*1114112;
  int b = r / 8704; r -= b*8704;
  int j = r / 256;  r -= j*256;
  int rs = r >> 3, ks = r & 7;
  int row = (rs>>3)*1024 + b*8 + (rs&7);
  int k0 = j*64 + ks*8;
  __hip_bfloat16* o = dst + (size_t)c*8;
  for (int e=0;e<8;++e){
    int k = k0+e; float v;
    if (k < 1024)      v = Wih1[((size_t)f*4096+row)*1152 + k];
    else if (k < 2048) v = Whh1[((size_t)f*4096+row)*1024 + (k-1024)];
    else               v = Wih1[((size_t)f*4096+row)*1152 + 1024 + (k-2048)];
    o[e] = __float2bfloat16(v);
  }
}

__global__ void k_pack2(const float* Wih2, const float* Whh2, __hip_bfloat16* dst){
  int c = blockIdx.x*256 + threadIdx.x; if (c >= 2*1048576) return;
  int f = c / 1048576; int r = c - f*1048576;
  int b = r / 8192; r -= b*8192;
  int j = r / 256;  r -= j*256;
  int rs = r >> 3, ks = r & 7;
  int row = (rs>>3)*1024 + b*8 + (rs&7);
  int k0 = j*64 + ks*8;
  __hip_bfloat16* o = dst + (size_t)c*8;
  for (int e=0;e<8;++e){
    int k = k0+e;
    float v = (k < 1024) ? Wih2[((size_t)f*4096+row)*1024 + k]
                         : Whh2[((size_t)f*4096+row)*1024 + (k-1024)];
    o[e] = __float2bfloat16(v);
  }
}

__global__ void k_packD(const float* Wd, __hip_bfloat16* dst){
  int c = blockIdx.x*256 + threadIdx.x; if (c >= 2*131072) return;
  int f = c / 131072; int r = c - f*131072;
  int b = r / 1024; r -= b*1024;
  int j = r / 256;  r -= j*256;
  int rr = r >> 5, k5 = r & 31;
  int row = b*8 + rr;
  int k0 = j*256 + k5*8;
  __hip_bfloat16* o = dst + (size_t)c*8;
  for (int e=0;e<8;++e)
    o[e] = __float2bfloat16(Wd[((size_t)f*1024 + (k0+e))*1024 + row]);
}

__global__ void k_packO(const float* Wo, __hip_bfloat16* dst){
  int c = blockIdx.x*256 + threadIdx.x; if (c >= 40960) return;
  int f = c / 20480; int r = c - f*20480;
  int b = r / 256; r -= b*256;
  int r2 = r >> 7, kk = r & 127;
  int row = r2*80 + b;
  int k0 = kk*8;
  __hip_bfloat16* o = dst + (size_t)c*8;
  for (int e=0;e<8;++e)
    o[e] = __float2bfloat16(Wo[((size_t)f*1024 + (k0+e))*160 + row]);
}

// ---------------- main persistent kernel ----------------
__launch_bounds__(256)
__global__ void k_flow(uint8_t* ws,
    const float* b_att_all, const float* b1_all, const float* b2_all,
    const float* bd_all, const float* bo_all, float* dout)
{
  const int tid = threadIdx.x, bid = blockIdx.x;
  const int rs = tid>>3, ks = tid&7;

  float* va  = (float*)(ws + OFF_VA);
  float* v1  = (float*)(ws + OFF_V1);
  float* v2  = (float*)(ws + OFF_V2);
  float* hdb = (float*)(ws + OFF_HD);
  float* seq = (float*)(ws + OFF_SEQ);
  float* scb = (float*)(ws + OFF_SC);
  const float* rb = (const float*)(ws + OFF_RB);
  int* slots = (int*)(ws + OFF_SL);
  int* flg   = (int*)(ws + OFF_FLG);
  int* attsl = (int*)(ws + OFF_ASL);
  const uint4* WAu = (const uint4*)(ws + OFF_WA);
  const uint4* W1u = (const uint4*)(ws + OFF_W1);
  const uint4* W2u = (const uint4*)(ws + OFF_W2);
  const uint4* WDu = (const uint4*)(ws + OFF_WD);
  const uint4* WOu = (const uint4*)(ws + OFF_WO);
  const uint4* WQu = (const uint4*)(ws + OFF_WQK);
  const uint4* WVu = (const uint4*)(ws + OFF_VAL);

  __shared__ __align__(16) float vst[2176];
  __shared__ __align__(16) float att_s[192];
  __shared__ float zred[64];
  __shared__ float cst[3][8];

  int epoch = 0;

  auto BAR = [&]() {
    __syncthreads();
    ++epoch;
    if (tid == 0) __hip_atomic_store(slots + bid, epoch, __ATOMIC_RELEASE, AG);
    for (;;) {
      int ok = 1;
      if (tid < GTOT) ok = (__hip_atomic_load(slots + tid, __ATOMIC_ACQUIRE, AG) >= epoch) ? 1 : 0;
      if (__syncthreads_and(ok)) break;
    }
  };
  auto STAGE = [&](const float* g, float* s, int n) {
    const unsigned long long* g8 = (const unsigned long long*)g;
    unsigned long long* s8 = (unsigned long long*)s;
    for (int i = tid; i < (n>>1); i += 256) s8[i] = aldx8(g8 + i);
    __syncthreads();
  };

  if (tid < 24) ((float*)cst)[tid] = 0.f;
  __syncthreads();

  for (int gs = 0; gs < 1024; ++gs) {
    const int fl  = (gs < 512) ? 1 : 0;        // flow param index (backward flow first)
    const int t   = (gs < 512) ? gs : gs - 512;
    const int col = (gs < 512) ? (511 - t) : t;
    const int p = gs & 1, q = p ^ 1;

    if (gs == 512) {  // flow transition: zero carries
      if (bid < GMAIN) {
        if (tid < 8) {
          int u = bid*8 + tid;
          astx(va + p*1152 + 80 + u, 0.f);
          astx(v1 + p*2176 + 1024 + u, 0.f);
          astx(v2 + p*2048 + 1024 + u, 0.f);
        }
        if (tid < 24) ((float*)cst)[tid] = 0.f;
      } else if (bid == GMAIN) {
        if (tid < 80) astx(va + p*1152 + tid, 0.f);
      }
      BAR();
    }

    if (bid < GMAIN) {
      // ===== phase A: attention-LSTM =====
      STAGE(va + p*1152, vst, 1152);
      {
        float acc = 0.f;
        size_t base = ((size_t)(fl*GMAIN + bid)*18)*256 + rs*8 + ks;
        #pragma unroll 6
        for (int j = 0; j < 18; ++j) acc += dot8(WAu[base + j*256], vst + j*64 + ks*8);
        acc += __shfl_xor(acc,1); acc += __shfl_xor(acc,2); acc += __shfl_xor(acc,4);
        if (ks == 0) {
          int row = (rs>>3)*1024 + bid*8 + (rs&7);
          zred[rs] = acc + b_att_all[fl*4096 + row];
        }
      }
      __syncthreads();
      if (tid < 8) {
        float zi=zred[tid], zf=zred[8+tid], zg=zred[16+tid], zo=zred[24+tid];
        float c = sigf(zf)*cst[0][tid] + sigf(zi)*tanhf_(zg);
        float h = sigf(zo)*tanhf_(c);
        cst[0][tid] = c;
        int u = bid*8 + tid;
        astx(v1 + p*2176 + u, h);
        astx(va + q*1152 + 80 + u, h);
      }
      BAR();  // ha visible

      // ===== phase C: LSTM1 ([ha|h1prev] first, ctx appended) =====
      STAGE(v1 + p*2176, vst, 2048);
      {
        float acc = 0.f;
        size_t base = ((size_t)(fl*GMAIN + bid)*34)*256 + rs*8 + ks;
        #pragma unroll 8
        for (int j = 0; j < 32; ++j) acc += dot8(W1u[base + j*256], vst + j*64 + ks*8);
        if (tid == 0) { while (__hip_atomic_load(flg, __ATOMIC_ACQUIRE, AG) < gs+1) {} }
        __syncthreads();
        {
          const unsigned long long* g8 = (const unsigned long long*)(v1 + p*2176 + 2048);
          unsigned long long* s8 = (unsigned long long*)(vst + 2048);
          if (tid < 64) s8[tid] = aldx8(g8 + tid);
        }
        __syncthreads();
        for (int j = 32; j < 34; ++j) acc += dot8(W1u[base + j*256], vst + j*64 + ks*8);
        acc += __shfl_xor(acc,1); acc += __shfl_xor(acc,2); acc += __shfl_xor(acc,4);
        if (ks == 0) {
          int row = (rs>>3)*1024 + bid*8 + (rs&7);
          zred[rs] = acc + b1_all[fl*4096 + row];
        }
      }
      __syncthreads();
      if (tid < 8) {
        float zi=zred[tid], zf=zred[8+tid], zg=zred[16+tid], zo=zred[24+tid];
        float c = sigf(zf)*cst[1][tid] + sigf(zi)*tanhf_(zg);
        float h = sigf(zo)*tanhf_(c);
        cst[1][tid] = c;
        int u = bid*8 + tid;
        astx(v2 + p*2048 + u, h);
        astx(v1 + q*2176 + 1024 + u, h);
      }
      BAR();  // h1 visible

      // ===== phase D: LSTM2 =====
      STAGE(v2 + p*2048, vst, 2048);
      {
        float acc = 0.f;
        size_t base = ((size_t)(fl*GMAIN + bid)*32)*256 + rs*8 + ks;
        #pragma unroll 8
        for (int j = 0; j < 32; ++j) acc += dot8(W2u[base + j*256], vst + j*64 + ks*8);
        acc += __shfl_xor(acc,1); acc += __shfl_xor(acc,2); acc += __shfl_xor(acc,4);
        if (ks == 0) {
          int row = (rs>>3)*1024 + bid*8 + (rs&7);
          zred[rs] = acc + b2_all[fl*4096 + row];
        }
      }
      __syncthreads();
      if (tid < 8) {
        float zi=zred[tid], zf=zred[8+tid], zg=zred[16+tid], zo=zred[24+tid];
        float c = sigf(zf)*cst[2][tid] + sigf(zi)*tanhf_(zg);
        float h = sigf(zo)*tanhf_(c);
        cst[2][tid] = c;
        astx(v2 + q*2048 + 1024 + bid*8 + tid, h);
      }
      BAR();  // h2 visible

      // ===== phase E: hd = tanh(h2@Wd + bd) =====
      STAGE(v2 + q*2048 + 1024, vst, 1024);
      {
        int r = tid>>5, k5 = tid&31;
        float acc = 0.f;
        size_t base = ((size_t)(fl*GMAIN + bid)*4)*256 + r*32 + k5;
        #pragma unroll
        for (int j = 0; j < 4; ++j) acc += dot8(WDu[base + j*256], vst + j*256 + k5*8);
        acc += __shfl_xor(acc,1); acc += __shfl_xor(acc,2); acc += __shfl_xor(acc,4);
        acc += __shfl_xor(acc,8); acc += __shfl_xor(acc,16);
        if (k5 == 0) {
          float hd = tanhf_(acc + bd_all[fl*1024 + bid*8 + r]);
          astx(hdb + bid*8 + r, hd);
        }
      }
      BAR();  // hd visible

      // ===== phase F: out = hd@Wo + bo ; coupling inverse =====
      if (bid < 80) {
        STAGE(hdb, vst, 1024);
        int r2 = tid>>7, kk = tid&127;
        uint4 w = WOu[((size_t)(fl*80 + bid)*2 + r2)*128 + kk];
        float a4 = dot8(w, vst + kk*8);
        a4 += __shfl_xor(a4,1); a4 += __shfl_xor(a4,2); a4 += __shfl_xor(a4,4);
        a4 += __shfl_xor(a4,8); a4 += __shfl_xor(a4,16); a4 += __shfl_xor(a4,32);
        if ((tid & 63) == 0) zred[tid>>6] = a4;
        __syncthreads();
        if (tid == 0) {
          float bp = zred[0] + zred[1] + bo_all[fl*160 + bid];
          float ls = zred[2] + zred[3] + bo_all[fl*160 + 80 + bid];
          float x = (fl == 1) ? rb[col*80 + bid] : aldx(seq + col*80 + bid);
          float y = (x - bp) * __expf(-ls);
          if (fl == 1) astx(seq + col*80 + bid, y);
          else         dout[bid*512 + col] = y;
          astx(va + q*1152 + bid, y);
        }
      }
      BAR();  // y visible -> next step
    } else {
      // ===== attention blocks (bid 128..135): scores / softmax / ctx =====
      const int abid = bid - GMAIN;
      BAR();  // wait for ha
      STAGE(v1 + p*2176, vst, 1024);
      if (tid < 192) {  // 24 rows x 8 k-slices
        float acc = 0.f;
        size_t base = ((size_t)(fl*8 + abid)*16)*192 + rs*8 + ks;
        #pragma unroll 8
        for (int j = 0; j < 16; ++j) acc += dot8(WQu[base + j*192], vst + j*64 + ks*8);
        acc += __shfl_xor(acc,1); acc += __shfl_xor(acc,2); acc += __shfl_xor(acc,4);
        if (ks == 0) astx(scb + abid*24 + rs, acc);
      }
      __syncthreads();
      if (tid == 0) __hip_atomic_store(attsl + abid, gs+1, __ATOMIC_RELEASE, AG);

      if (abid == 0) {  // collector: softmax + ctx
        for (;;) {
          int ok = 1;
          if (tid < 8) ok = (__hip_atomic_load(attsl + tid, __ATOMIC_ACQUIRE, AG) >= gs+1) ? 1 : 0;
          if (__syncthreads_and(ok)) break;
        }
        if (tid < 96) ((unsigned long long*)att_s)[tid] = aldx8(((const unsigned long long*)scb) + tid);
        __syncthreads();
        if (tid < 64) {
          float m = fmaxf(att_s[tid], fmaxf(att_s[tid+64], att_s[tid+128]));
          #pragma unroll
          for (int d=1; d<64; d<<=1) m = fmaxf(m, __shfl_xor(m, d));
          if (tid == 0) zred[0] = m;
        }
        __syncthreads();
        { float mx = zred[0]; if (tid < 192) att_s[tid] = __expf(att_s[tid] - mx); }
        __syncthreads();
        if (tid < 64) {
          float s2 = att_s[tid] + att_s[tid+64] + att_s[tid+128];
          #pragma unroll
          for (int d=1; d<64; d<<=1) s2 += __shfl_xor(s2, d);
          if (tid == 0) zred[1] = 1.f / s2;
        }
        __syncthreads();
        if (tid < 192) att_s[tid] *= zred[1];
        __syncthreads();
        for (int p4 = 0; p4 < 4; ++p4) {
          float acc = 0.f;
          size_t base = ((size_t)(fl*4 + p4)*3)*256 + rs*8 + ks;
          #pragma unroll
          for (int j = 0; j < 3; ++j) acc += dot8(WVu[base + j*256], att_s + j*64 + ks*8);
          acc += __shfl_xor(acc,1); acc += __shfl_xor(acc,2); acc += __shfl_xor(acc,4);
          if (ks == 0) astx(v1 + p*2176 + 2048 + p4*32 + rs, acc);
        }
        __syncthreads();
        if (tid == 0) __hip_atomic_store(flg, gs+1, __ATOMIC_RELEASE, AG);
      }
      BAR();  // C
      BAR();  // D
      BAR();  // E
      BAR();  // F
    }
  }
}

// ---------------- launch ----------------
extern "C" void kernel_launch(void* const* d_in, const int* in_sizes, int n_in,
                              void* d_out, int out_size, void* d_ws, size_t ws_size,
                              hipStream_t stream) {
  if (ws_size < NEEDED) return;  // insufficient scratch; cannot run
  uint8_t* ws = (uint8_t*)d_ws;
  const float* residual = (const float*)d_in[0];
  const float* spk      = (const float*)d_in[1];
  const float* emb      = (const float*)d_in[2];
  const float* Wih_att  = (const float*)d_in[3];
  const float* Whh_att  = (const float*)d_in[4];
  const float* b_att    = (const float*)d_in[5];
  const float* Wq       = (const float*)d_in[6];
  const float* Wk       = (const float*)d_in[7];
  const float* Wv       = (const float*)d_in[8];
  const float* Wih1     = (const float*)d_in[9];
  const float* Whh1     = (const float*)d_in[10];
  const float* b1       = (const float*)d_in[11];
  const float* Wih2     = (const float*)d_in[12];
  const float* Whh2     = (const float*)d_in[13];
  const float* b2       = (const float*)d_in[14];
  const float* Wd       = (const float*)d_in[15];
  const float* bd       = (const float*)d_in[16];
  const float* Wo       = (const float*)d_in[17];
  const float* bo       = (const float*)d_in[18];
  const int*   text     = (const int*)d_in[21];

  dim3 B(256);
  k_init<<<49, B, 0, stream>>>((float*)(ws+OFF_VA), (int)((NEEDED-OFF_VA)/4));
  k_rbuf<<<160, B, 0, stream>>>(residual, (float*)(ws+OFF_RB));
  k_enc<<<480, B, 0, stream>>>(emb, spk, text, (float*)(ws+OFF_ENC));
  k_keysvals<<<192, B, 0, stream>>>((const float*)(ws+OFF_ENC), Wk, Wv,
                                    (float*)(ws+OFF_KEY), (__hip_bfloat16*)(ws+OFF_VAL));
  k_wqk<<<1536, B, 0, stream>>>(Wq, (const float*)(ws+OFF_KEY), (__hip_bfloat16*)(ws+OFF_WQK));
  k_packA<<<4608, B, 0, stream>>>(Wih_att, Whh_att, (__hip_bfloat16*)(ws+OFF_WA));
  k_pack1<<<8704, B, 0, stream>>>(Wih1, Whh1, (__hip_bfloat16*)(ws+OFF_W1));
  k_pack2<<<8192, B, 0, stream>>>(Wih2, Whh2, (__hip_bfloat16*)(ws+OFF_W2));
  k_packD<<<1024, B, 0, stream>>>(Wd, (__hip_bfloat16*)(ws+OFF_WD));
  k_packO<<<160, B, 0, stream>>>(Wo, (__hip_bfloat16*)(ws+OFF_WO));
  k_flow<<<GTOT, B, 0, stream>>>(ws, b_att, b1, b2, bd, bo, (float*)d_out);
}

// Round 2
// 92782.550 us; speedup vs baseline: 1.0413x; 1.0413x over previous
//
#include <hip/hip_runtime.h>
#include <hip/hip_bf16.h>
#include <stdint.h>

#define AG __HIP_MEMORY_SCOPE_AGENT

// ---------------- workspace layout (bytes) ----------------
static constexpr size_t OFF_WA  = 0;                 // [2][256][256][9] uint4 (att-LSTM regs)
static constexpr size_t OFF_W1  = 18874368;          // [2][256][16][2184] bf16 (LDS image)
static constexpr size_t OFF_W2  = 54657024;          // [2][256][16][2056] bf16 (LDS image)
static constexpr size_t OFF_WD  = 88342528;          // [2][256][256][2] uint4 (Wd regs)
static constexpr size_t OFF_WO  = 92536832;          // [2][80][256][2] uint2 (Wo regs)
static constexpr size_t OFF_WQ  = 93192192;          // [2][192][256] uint2 (Wq@keys^T * inv)
static constexpr size_t OFF_VL  = 93978624;          // [2][8][256][2] uint4 (vals regs)
static constexpr size_t OFF_KEY = 94109696;          // [2][192][128] f32
static constexpr size_t OFF_V32 = 94306304;          // [2][192][128] f32 vals
static constexpr size_t OFF_WQT = 94502912;          // [2][128][1024] f32 Wq^T
static constexpr size_t OFF_ENC = 95551488;          // [192][640] f32
static constexpr size_t OFF_RB  = 96043008;          // residual^T [512][80] f32
static constexpr size_t OFF_SEQ = 96206848;          // intermediate seq [512][80] f32
static constexpr size_t OFF_DYN = 96370688;
static constexpr size_t OFF_VAb = OFF_DYN + 0;       // [2][1152] f32: [y(80)|ha(1024)|pad]
static constexpr size_t OFF_V1b = OFF_DYN + 9216;    // [2][2176] f32: [ha|h1prev|ctx]
static constexpr size_t OFF_V2b = OFF_DYN + 26624;   // [2][2048] f32: [h1|h2prev]
static constexpr size_t OFF_HDb = OFF_DYN + 43008;   // [1024] f32
static constexpr size_t OFF_SCb = OFF_DYN + 47104;   // [192] f32 scores
static constexpr size_t OFF_SFb = OFF_DYN + 48128;   // [192] int score flags
static constexpr size_t OFF_CFb = OFF_DYN + 49152;   // [8] int ctx flags
static constexpr size_t OFF_SLb = OFF_DYN + 49408;   // [256] int barrier slots
static constexpr size_t DYN_BYTES = 50432;
static constexpr size_t NEEDED = OFF_DYN + DYN_BYTES;

// ---------------- device helpers ----------------
__device__ __forceinline__ float aldx(const float* p){ return __hip_atomic_load(p, __ATOMIC_RELAXED, AG); }
__device__ __forceinline__ void  astx(float* p, float v){ __hip_atomic_store(p, v, __ATOMIC_RELAXED, AG); }
__device__ __forceinline__ int   ldi(const int* p){ return __hip_atomic_load(p, __ATOMIC_RELAXED, AG); }

__device__ __forceinline__ float dot8(uint4 w, const float* v){
  float4 a = *(const float4*)v;
  float4 b = *(const float4*)(v+4);
  float s;
  s = __uint_as_float(w.x << 16) * a.x;
  s = fmaf(__uint_as_float(w.x & 0xffff0000u), a.y, s);
  s = fmaf(__uint_as_float(w.y << 16),         a.z, s);
  s = fmaf(__uint_as_float(w.y & 0xffff0000u), a.w, s);
  s = fmaf(__uint_as_float(w.z << 16),         b.x, s);
  s = fmaf(__uint_as_float(w.z & 0xffff0000u), b.y, s);
  s = fmaf(__uint_as_float(w.w << 16),         b.z, s);
  s = fmaf(__uint_as_float(w.w & 0xffff0000u), b.w, s);
  return s;
}
__device__ __forceinline__ float dot4(uint2 w, const float* v){
  float4 a = *(const float4*)v;
  float s;
  s = __uint_as_float(w.x << 16) * a.x;
  s = fmaf(__uint_as_float(w.x & 0xffff0000u), a.y, s);
  s = fmaf(__uint_as_float(w.y << 16),         a.z, s);
  s = fmaf(__uint_as_float(w.y & 0xffff0000u), a.w, s);
  return s;
}
__device__ __forceinline__ float sigf(float x){ return 1.f/(1.f+__expf(-x)); }
__device__ __forceinline__ float tanhf_(float x){
  x = fminf(12.f, fmaxf(-12.f, x));
  float t = __expf(2.f*x);
  return (t-1.f)/(t+1.f);
}

// ---------------- prep kernels ----------------
__global__ void k_init(float* z, int n){ int i = blockIdx.x*256 + threadIdx.x; if (i<n) z[i]=0.f; }

__global__ void k_rbuf(const float* res, float* rb){
  int i = blockIdx.x*256 + threadIdx.x; if (i >= 512*80) return;
  int t = i/80, m = i - t*80;
  rb[i] = res[m*512 + t];
}

__global__ void k_enc(const float* emb, const float* spk, const int* text, float* enc){
  int i = blockIdx.x*256 + threadIdx.x; if (i >= 192*640) return;
  int s = i/640, e = i - s*640;
  enc[i] = (e < 512) ? emb[(size_t)text[s]*512 + e] : spk[e-512];
}

__global__ void k_keysvals(const float* enc, const float* Wk, const float* Wv,
                           float* keys, float* vals32){
  int i = blockIdx.x*256 + threadIdx.x; if (i >= 2*192*128) return;
  int f = i/(192*128); int r = i - f*192*128; int s = r/128, a = r - s*128;
  float ka=0.f, va=0.f;
  for (int e=0;e<640;++e){
    float x = enc[s*640+e];
    ka = fmaf(x, Wk[((size_t)f*640+e)*128+a], ka);
    va = fmaf(x, Wv[((size_t)f*640+e)*128+a], va);
  }
  keys[((size_t)f*192+s)*128+a] = ka;
  vals32[((size_t)f*192+s)*128+a] = va;
}

__global__ void k_wqT(const float* Wq, float* WqT){
  int i = blockIdx.x*256 + threadIdx.x; if (i >= 2*128*1024) return;
  int f = i/(128*1024); int r = i - f*128*1024; int a = r/1024, h = r - a*1024;
  WqT[i] = Wq[((size_t)f*1024+h)*128+a];
}

// one block per (f,s): WQK packed row s, uint2 (4 bf16) per thread
__global__ void k_wqk2(const float* WqT, const float* keys, uint2* dst){
  int b = blockIdx.x; int f = b/192, s = b - f*192;
  int t = threadIdx.x;
  float4 acc = {0.f,0.f,0.f,0.f};
  const float* kp = keys + ((size_t)f*192+s)*128;
  const float* wp = WqT + (size_t)f*128*1024 + t*4;
  for (int a=0;a<128;++a){
    float kk = kp[a];
    float4 w = *(const float4*)(wp + (size_t)a*1024);
    acc.x = fmaf(kk, w.x, acc.x); acc.y = fmaf(kk, w.y, acc.y);
    acc.z = fmaf(kk, w.z, acc.z); acc.w = fmaf(kk, w.w, acc.w);
  }
  const float inv = 0.08838834764831845f;
  __hip_bfloat16 b0 = __float2bfloat16(acc.x*inv), b1 = __float2bfloat16(acc.y*inv);
  __hip_bfloat16 b2 = __float2bfloat16(acc.z*inv), b3 = __float2bfloat16(acc.w*inv);
  uint2 o;
  o.x = (uint32_t)(*(uint16_t*)&b0) | ((uint32_t)(*(uint16_t*)&b1) << 16);
  o.y = (uint32_t)(*(uint16_t*)&b2) | ((uint32_t)(*(uint16_t*)&b3) << 16);
  dst[((size_t)f*192+s)*256 + t] = o;
}

__device__ __forceinline__ uint32_t pk2(float a, float b){
  __hip_bfloat16 x = __float2bfloat16(a), y = __float2bfloat16(b);
  return (uint32_t)(*(uint16_t*)&x) | ((uint32_t)(*(uint16_t*)&y) << 16);
}

__global__ void k_packV(const float* vals32, uint4* dst){
  int i = blockIdx.x*256 + threadIdx.x; if (i >= 2*8*256*2) return;
  int j = i & 1; int r = i >> 1;
  int t = r & 255; r >>= 8;
  int ab = r & 7; int f = r >> 3;
  int a = ab*16 + (t>>4);
  int s0 = (t&15)*8 + j*128;
  float v[8];
  for (int e=0;e<8;++e){ int s = s0+e; v[e] = (s<192) ? vals32[((size_t)f*192+s)*128+a] : 0.f; }
  uint4 o; o.x = pk2(v[0],v[1]); o.y = pk2(v[2],v[3]); o.z = pk2(v[4],v[5]); o.w = pk2(v[6],v[7]);
  dst[i] = o;
}

__global__ void k_packA2(const float* Wih, const float* Whh, uint4* dst){
  int i = blockIdx.x*256 + threadIdx.x; if (i >= 2*256*256*9) return;
  int j = i % 9; int r = i / 9;
  int t = r & 255; r >>= 8;
  int b = r & 255; int f = r >> 8;
  int rs = t>>4, ks = t&15;
  int row = (rs>>2)*1024 + b*4 + (rs&3);
  int c0 = j*128 + ks*8;
  float v[8];
  for (int e=0;e<8;++e){
    int c = c0+e;
    v[e] = (c<80) ? Wih[((size_t)f*4096+row)*80 + c]
         : (c<1104) ? Whh[((size_t)f*4096+row)*1024 + (c-80)] : 0.f;
  }
  uint4 o; o.x = pk2(v[0],v[1]); o.y = pk2(v[2],v[3]); o.z = pk2(v[4],v[5]); o.w = pk2(v[6],v[7]);
  dst[i] = o;
}

__global__ void k_pack1b(const float* Wih1, const float* Whh1, uint4* dst){
  int i = blockIdx.x*256 + threadIdx.x; if (i >= 2*256*16*273) return;
  int kc = i % 273; int r = i / 273;
  int rr = r & 15; r >>= 4;
  int b = r & 255; int f = r >> 8;
  int row = (rr>>2)*1024 + b*4 + (rr&3);
  int k0 = kc*8;
  float v[8];
  for (int e=0;e<8;++e){
    int k = k0+e; float x;
    if (k < 1024)      x = Wih1[((size_t)f*4096+row)*1152 + k];
    else if (k < 2048) x = Whh1[((size_t)f*4096+row)*1024 + (k-1024)];
    else if (k < 2176) x = Wih1[((size_t)f*4096+row)*1152 + 1024 + (k-2048)];
    else               x = 0.f;
    v[e] = x;
  }
  uint4 o; o.x = pk2(v[0],v[1]); o.y = pk2(v[2],v[3]); o.z = pk2(v[4],v[5]); o.w = pk2(v[6],v[7]);
  dst[i] = o;
}

__global__ void k_pack2b(const float* Wih2, const float* Whh2, uint4* dst){
  int i = blockIdx.x*256 + threadIdx.x; if (i >= 2*256*16*257) return;
  int kc = i % 257; int r = i / 257;
  int rr = r & 15; r >>= 4;
  int b = r & 255; int f = r >> 8;
  int row = (rr>>2)*1024 + b*4 + (rr&3);
  int k0 = kc*8;
  float v[8];
  for (int e=0;e<8;++e){
    int k = k0+e;
    v[e] = (k < 1024) ? Wih2[((size_t)f*4096+row)*1024 + k]
         : (k < 2048) ? Whh2[((size_t)f*4096+row)*1024 + (k-1024)] : 0.f;
  }
  uint4 o; o.x = pk2(v[0],v[1]); o.y = pk2(v[2],v[3]); o.z = pk2(v[4],v[5]); o.w = pk2(v[6],v[7]);
  dst[i] = o;
}

// tiled transpose pack of Wd: grid 2*16*16 blocks
__global__ void k_packD2(const float* Wd, uint4* dst){
  __shared__ float tile[64][65];
  int b = blockIdx.x; int f = b >> 8; int rem = b & 255;
  int ot = rem >> 4, ct = rem & 15;
  int tid = threadIdx.x;
  for (int i = tid; i < 4096; i += 256){
    int rc = i >> 6, oc = i & 63;
    tile[rc][oc] = Wd[((size_t)f*1024 + ct*64 + rc)*1024 + ot*64 + oc];
  }
  __syncthreads();
  for (int w = 0; w < 2; ++w){
    int idx = w*256 + tid;
    int op = idx >> 3, cc = idx & 7;
    int k6 = (ct&7)*8 + cc, j = ct >> 3;
    int o = ot*64 + op;
    int b2 = o >> 2, r2 = o & 3;
    uint4 out;
    out.x = pk2(tile[cc*8+0][op], tile[cc*8+1][op]);
    out.y = pk2(tile[cc*8+2][op], tile[cc*8+3][op]);
    out.z = pk2(tile[cc*8+4][op], tile[cc*8+5][op]);
    out.w = pk2(tile[cc*8+6][op], tile[cc*8+7][op]);
    dst[((((size_t)f*256 + b2)*256) + r2*64 + k6)*2 + j] = out;
  }
}

__global__ void k_packO2(const float* Wo, uint2* dst){
  int i = blockIdx.x*256 + threadIdx.x; if (i >= 2*80*256) return;
  int t = i & 255; int r = i >> 8;
  int m = r % 80; int f = r / 80;
  for (int j = 0; j < 2; ++j){
    int row = m + j*80;
    float v[4];
    for (int e=0;e<4;++e) v[e] = Wo[((size_t)f*1024 + t*4+e)*160 + row];
    uint2 o; o.x = pk2(v[0],v[1]); o.y = pk2(v[2],v[3]);
    dst[(size_t)i*2 + j] = o;
  }
}

// ---------------- main persistent kernel (one flow) ----------------
__launch_bounds__(256)
__global__ void k_flow2(uint8_t* ws, int fl, int rev, int out_mode,
    const float* b_att_all, const float* b1_all, const float* b2_all,
    const float* bd_all, const float* bo_all,
    const float* xsrc, float* ydst)
{
  const int tid = threadIdx.x, bid = blockIdx.x;
  const int rs = tid >> 4, ks = tid & 15;   // 16 rows x 16 k-slices
  const int wid = tid >> 6;

  float* va  = (float*)(ws + OFF_VAb);
  float* v1  = (float*)(ws + OFF_V1b);
  float* v2  = (float*)(ws + OFF_V2b);
  float* hdb = (float*)(ws + OFF_HDb);
  float* scb = (float*)(ws + OFF_SCb);
  int* sflag = (int*)(ws + OFF_SFb);
  int* cflag = (int*)(ws + OFF_CFb);
  int* slots = (int*)(ws + OFF_SLb);

  __shared__ __align__(16) ushort W1s[16*2184];
  __shared__ __align__(16) ushort W2s[16*2056];
  __shared__ __align__(16) float vst[2208];
  __shared__ __align__(16) float att_s[256];
  __shared__ float zred[32];
  __shared__ float cst[3][4];
  __shared__ float bAs[16], b1s[16], b2s[16], bds[4], bos[2];

  const size_t fb = (size_t)fl*256 + bid;

  // ---- prologue: weights to LDS / regs ----
  { const uint4* src = (const uint4*)((const ushort*)(ws + OFF_W1) + fb*16*2184);
    uint4* dst = (uint4*)W1s;
    for (int i = tid; i < 4368; i += 256) dst[i] = src[i]; }
  { const uint4* src = (const uint4*)((const ushort*)(ws + OFF_W2) + fb*16*2056);
    uint4* dst = (uint4*)W2s;
    for (int i = tid; i < 4112; i += 256) dst[i] = src[i]; }
  uint4 wa[9];
  { const uint4* g = (const uint4*)(ws + OFF_WA) + (fb*256 + tid)*9;
    #pragma unroll
    for (int j = 0; j < 9; ++j) wa[j] = g[j]; }
  uint4 wd[2];
  { const uint4* g = (const uint4*)(ws + OFF_WD) + (fb*256 + tid)*2;
    wd[0] = g[0]; wd[1] = g[1]; }
  uint2 wqk = {0,0};
  if (bid >= 64) wqk = ((const uint2*)(ws + OFF_WQ))[((size_t)fl*192 + (bid-64))*256 + tid];
  uint4 vr0 = {0,0,0,0}, vr1 = {0,0,0,0};
  if (bid < 8){ const uint4* g = (const uint4*)(ws + OFF_VL) + (((size_t)fl*8 + bid)*256 + tid)*2;
    vr0 = g[0]; vr1 = g[1]; }
  uint2 wo0 = {0,0}, wo1 = {0,0};
  if (bid < 80){ const uint2* g = (const uint2*)(ws + OFF_WO) + (((size_t)fl*80 + bid)*256 + tid)*2;
    wo0 = g[0]; wo1 = g[1]; }
  if (tid < 16){
    int g = tid >> 2, uu = tid & 3;
    bAs[tid] = b_att_all[fl*4096 + g*1024 + bid*4 + uu];
    b1s[tid] = b1_all  [fl*4096 + g*1024 + bid*4 + uu];
    b2s[tid] = b2_all  [fl*4096 + g*1024 + bid*4 + uu];
  }
  if (tid < 4)  bds[tid] = bd_all[fl*1024 + bid*4 + tid];
  if (tid < 2 && bid < 80) bos[tid] = bo_all[fl*160 + tid*80 + bid];
  if (tid < 12) ((float*)cst)[tid] = 0.f;
  __syncthreads();

  int epoch = 0;
  auto BAR = [&]() {
    __syncthreads();
    ++epoch;
    if (tid == 0) __hip_atomic_store(slots + bid, epoch, __ATOMIC_RELEASE, AG);
    for (;;) {
      int ok = (ldi(slots + tid) >= epoch) ? 1 : 0;
      if (__syncthreads_and(ok)) break;
      __builtin_amdgcn_s_sleep(1);
    }
    __builtin_amdgcn_fence(__ATOMIC_ACQUIRE, "agent");
  };

  for (int t = 0; t < 512; ++t) {
    const int col = rev ? (511 - t) : t;
    const int p = t & 1, q = p ^ 1;

    // ===== phase A: attention-LSTM (K=1152: y|ha|pad) =====
    { const float4* g4 = (const float4*)(va + p*1152); float4* s4 = (float4*)vst;
      for (int i = tid; i < 288; i += 256)
        s4[i] = (i < 276) ? g4[i] : make_float4(0.f,0.f,0.f,0.f);
      __syncthreads(); }
    {
      float acc = 0.f;
      #pragma unroll
      for (int j = 0; j < 9; ++j) acc += dot8(wa[j], vst + j*128 + ks*8);
      acc += __shfl_xor(acc,1); acc += __shfl_xor(acc,2);
      acc += __shfl_xor(acc,4); acc += __shfl_xor(acc,8);
      if (ks == 0) zred[rs] = acc + bAs[rs];
    }
    __syncthreads();
    if (tid < 4) {
      float zi=zred[tid], zf=zred[4+tid], zg=zred[8+tid], zo=zred[12+tid];
      float c = sigf(zf)*cst[0][tid] + sigf(zi)*tanhf_(zg);
      float h = sigf(zo)*tanhf_(c);
      cst[0][tid] = c;
      astx(v1 + p*2176 + bid*4 + tid, h);
      astx(va + q*1152 + 80 + bid*4 + tid, h);
    }
    BAR();  // ha visible

    // ===== phase C: scores + ctx + LSTM1 (K=2176: ha|h1prev|ctx) =====
    { const float4* g4 = (const float4*)(v1 + p*2176); float4* s4 = (float4*)vst;
      for (int i = tid; i < 512; i += 256) s4[i] = g4[i];
      __syncthreads(); }
    if (bid >= 64) {  // score row s = bid-64
      float sv = dot4(wqk, vst + tid*4);
      #pragma unroll
      for (int d=1; d<64; d<<=1) sv += __shfl_xor(sv, d);
      if ((tid&63) == 0) zred[16+wid] = sv;
      __syncthreads();
      if (tid == 0) {
        int s = bid - 64;
        astx(scb + s, zred[16]+zred[17]+zred[18]+zred[19]);
        __hip_atomic_store(sflag + s, t+1, __ATOMIC_RELEASE, AG);
      }
    }
    if (bid < 8) {    // ctx block: softmax + ctx slice
      for (;;) {
        int ok = (tid < 192) ? ((ldi(sflag + tid) >= t+1) ? 1 : 0) : 1;
        if (__syncthreads_and(ok)) break;
        __builtin_amdgcn_s_sleep(1);
      }
      __builtin_amdgcn_fence(__ATOMIC_ACQUIRE, "agent");
      float v = (tid < 192) ? aldx(scb + tid) : -3.0e38f;
      float m = v;
      #pragma unroll
      for (int d=1; d<64; d<<=1) m = fmaxf(m, __shfl_xor(m, d));
      if ((tid&63) == 0) zred[16+wid] = m;
      __syncthreads();
      float mx = fmaxf(fmaxf(zred[16],zred[17]), fmaxf(zred[18],zred[19]));
      float e = (tid < 192) ? __expf(v - mx) : 0.f;
      float sm = e;
      #pragma unroll
      for (int d=1; d<64; d<<=1) sm += __shfl_xor(sm, d);
      if ((tid&63) == 0) zred[20+wid] = sm;
      __syncthreads();
      float inv = 1.f / (zred[20]+zred[21]+zred[22]+zred[23]);
      att_s[tid] = e * inv;
      __syncthreads();
      {
        float acc = dot8(vr0, att_s + ks*8) + dot8(vr1, att_s + 128 + ks*8);
        acc += __shfl_xor(acc,1); acc += __shfl_xor(acc,2);
        acc += __shfl_xor(acc,4); acc += __shfl_xor(acc,8);
        if (ks == 0) astx(v1 + p*2176 + 2048 + bid*16 + rs, acc);
      }
      __syncthreads();
      if (tid == 0) __hip_atomic_store(cflag + bid, t+1, __ATOMIC_RELEASE, AG);
    }
    float acc1 = 0.f;
    { const uint4* w1row = (const uint4*)(W1s) + (size_t)rs*273;
      #pragma unroll
      for (int j = 0; j < 16; ++j) acc1 += dot8(w1row[j*16 + ks], vst + j*128 + ks*8);
      for (;;) {
        int ok = (tid < 8) ? ((ldi(cflag + tid) >= t+1) ? 1 : 0) : 1;
        if (__syncthreads_and(ok)) break;
        __builtin_amdgcn_s_sleep(1);
      }
      __builtin_amdgcn_fence(__ATOMIC_ACQUIRE, "agent");
      if (tid < 128) vst[2048 + tid] = aldx(v1 + p*2176 + 2048 + tid);
      __syncthreads();
      acc1 += dot8(w1row[16*16 + ks], vst + 16*128 + ks*8);
      acc1 += __shfl_xor(acc1,1); acc1 += __shfl_xor(acc1,2);
      acc1 += __shfl_xor(acc1,4); acc1 += __shfl_xor(acc1,8);
      if (ks == 0) zred[rs] = acc1 + b1s[rs];
    }
    __syncthreads();
    if (tid < 4) {
      float zi=zred[tid], zf=zred[4+tid], zg=zred[8+tid], zo=zred[12+tid];
      float c = sigf(zf)*cst[1][tid] + sigf(zi)*tanhf_(zg);
      float h = sigf(zo)*tanhf_(c);
      cst[1][tid] = c;
      astx(v2 + p*2048 + bid*4 + tid, h);
      astx(v1 + q*2176 + 1024 + bid*4 + tid, h);
    }
    BAR();  // h1 visible

    // ===== phase D: LSTM2 (K=2048: h1|h2prev) =====
    { const float4* g4 = (const float4*)(v2 + p*2048); float4* s4 = (float4*)vst;
      for (int i = tid; i < 512; i += 256) s4[i] = g4[i];
      __syncthreads(); }
    {
      float acc = 0.f;
      const uint4* w2row = (const uint4*)(W2s) + (size_t)rs*257;
      #pragma unroll
      for (int j = 0; j < 16; ++j) acc += dot8(w2row[j*16 + ks], vst + j*128 + ks*8);
      acc += __shfl_xor(acc,1); acc += __shfl_xor(acc,2);
      acc += __shfl_xor(acc,4); acc += __shfl_xor(acc,8);
      if (ks == 0) zred[rs] = acc + b2s[rs];
    }
    __syncthreads();
    if (tid < 4) {
      float zi=zred[tid], zf=zred[4+tid], zg=zred[8+tid], zo=zred[12+tid];
      float c = sigf(zf)*cst[2][tid] + sigf(zi)*tanhf_(zg);
      float h = sigf(zo)*tanhf_(c);
      cst[2][tid] = c;
      astx(v2 + q*2048 + 1024 + bid*4 + tid, h);
    }
    BAR();  // h2 visible

    // ===== phase E: hd = tanh(h2@Wd + bd) =====
    { const float4* g4 = (const float4*)(v2 + q*2048 + 1024); float4* s4 = (float4*)vst;
      if (tid < 256) s4[tid] = g4[tid];
      __syncthreads(); }
    {
      int r2 = tid >> 6, k6 = tid & 63;
      float acc = dot8(wd[0], vst + k6*8) + dot8(wd[1], vst + 512 + k6*8);
      #pragma unroll
      for (int d=1; d<64; d<<=1) acc += __shfl_xor(acc, d);
      if ((tid & 63) == 0) {
        float hd = tanhf_(acc + bds[r2]);
        astx(hdb + bid*4 + r2, hd);
      }
    }
    BAR();  // hd visible

    // ===== phase F: out = hd@Wo + bo ; coupling inverse =====
    if (bid < 80) {
      float x = xsrc[col*80 + bid];       // issue early, overlaps stage
      { const float4* g4 = (const float4*)hdb; float4* s4 = (float4*)vst;
        if (tid < 256) s4[tid] = g4[tid];
        __syncthreads(); }
      float pb = dot4(wo0, vst + tid*4);
      float pl = dot4(wo1, vst + tid*4);
      #pragma unroll
      for (int d=1; d<64; d<<=1) { pb += __shfl_xor(pb, d); pl += __shfl_xor(pl, d); }
      if ((tid & 63) == 0) { zred[16+wid] = pb; zred[20+wid] = pl; }
      __syncthreads();
      if (tid == 0) {
        float bp = zred[16]+zred[17]+zred[18]+zred[19] + bos[0];
        float ls = zred[20]+zred[21]+zred[22]+zred[23] + bos[1];
        float y = (x - bp) * __expf(-ls);
        if (out_mode == 0) ydst[col*80 + bid] = y;
        else               ydst[bid*512 + col] = y;
        astx(va + q*1152 + bid, y);
      }
    }
    BAR();  // y visible -> next step
  }
}

// ---------------- launch ----------------
extern "C" void kernel_launch(void* const* d_in, const int* in_sizes, int n_in,
                              void* d_out, int out_size, void* d_ws, size_t ws_size,
                              hipStream_t stream) {
  if (ws_size < NEEDED) return;
  uint8_t* ws = (uint8_t*)d_ws;
  const float* residual = (const float*)d_in[0];
  const float* spk      = (const float*)d_in[1];
  const float* emb      = (const float*)d_in[2];
  const float* Wih_att  = (const float*)d_in[3];
  const float* Whh_att  = (const float*)d_in[4];
  const float* b_att    = (const float*)d_in[5];
  const float* Wq       = (const float*)d_in[6];
  const float* Wk       = (const float*)d_in[7];
  const float* Wv       = (const float*)d_in[8];
  const float* Wih1     = (const float*)d_in[9];
  const float* Whh1     = (const float*)d_in[10];
  const float* b1       = (const float*)d_in[11];
  const float* Wih2     = (const float*)d_in[12];
  const float* Whh2     = (const float*)d_in[13];
  const float* b2       = (const float*)d_in[14];
  const float* Wd       = (const float*)d_in[15];
  const float* bd       = (const float*)d_in[16];
  const float* Wo       = (const float*)d_in[17];
  const float* bo       = (const float*)d_in[18];
  const int*   text     = (const int*)d_in[21];

  dim3 B(256);
  k_rbuf<<<160, B, 0, stream>>>(residual, (float*)(ws+OFF_RB));
  k_enc<<<480, B, 0, stream>>>(emb, spk, text, (float*)(ws+OFF_ENC));
  k_keysvals<<<192, B, 0, stream>>>((const float*)(ws+OFF_ENC), Wk, Wv,
                                    (float*)(ws+OFF_KEY), (float*)(ws+OFF_V32));
  k_wqT<<<1024, B, 0, stream>>>(Wq, (float*)(ws+OFF_WQT));
  k_wqk2<<<384, B, 0, stream>>>((const float*)(ws+OFF_WQT), (const float*)(ws+OFF_KEY),
                                (uint2*)(ws+OFF_WQ));
  k_packV<<<32, B, 0, stream>>>((const float*)(ws+OFF_V32), (uint4*)(ws+OFF_VL));
  k_packA2<<<4608, B, 0, stream>>>(Wih_att, Whh_att, (uint4*)(ws+OFF_WA));
  k_pack1b<<<8736, B, 0, stream>>>(Wih1, Whh1, (uint4*)(ws+OFF_W1));
  k_pack2b<<<8224, B, 0, stream>>>(Wih2, Whh2, (uint4*)(ws+OFF_W2));
  k_packD2<<<512, B, 0, stream>>>(Wd, (uint4*)(ws+OFF_WD));
  k_packO2<<<160, B, 0, stream>>>(Wo, (uint2*)(ws+OFF_WO));

  // flow 1 (backward): rb -> seq
  k_init<<<50, B, 0, stream>>>((float*)(ws+OFF_DYN), (int)(DYN_BYTES/4));
  k_flow2<<<256, B, 0, stream>>>(ws, 1, 1, 0, b_att, b1, b2, bd, bo,
                                 (const float*)(ws+OFF_RB), (float*)(ws+OFF_SEQ));
  // flow 0 (forward): seq -> dout
  k_init<<<50, B, 0, stream>>>((float*)(ws+OFF_DYN), (int)(DYN_BYTES/4));
  k_flow2<<<256, B, 0, stream>>>(ws, 0, 0, 1, b_att, b1, b2, bd, bo,
                                 (const float*)(ws+OFF_SEQ), (float*)d_out);
}

// Round 3
// 30100.995 us; speedup vs baseline: 3.2098x; 3.0824x over previous
//
#include <hip/hip_runtime.h>
#include <hip/hip_bf16.h>
#include <stdint.h>

#define AG __HIP_MEMORY_SCOPE_AGENT
typedef unsigned long long ull;

// ---------------- workspace layout (bytes) ----------------
static constexpr size_t OFF_WA  = 0;                 // [2][256][256][9] uint4 (att-LSTM regs; j0=y-chunk, j1..8=haPrev)
static constexpr size_t OFF_W1  = 18874368;          // [2][256][16][2184] bf16 (LDS image, K=2176+pad)
static constexpr size_t OFF_W2  = 54657024;          // [2][256][16][2056] bf16 (LDS image, K=2048+pad)
static constexpr size_t OFF_WD  = 88342528;          // [2][256][256][2] uint4 (Wd regs)
static constexpr size_t OFF_WO  = 92536832;          // [2][80][256][2] uint2 (Wo regs)
static constexpr size_t OFF_WQ  = 93192192;          // [2][192][256] uint2 (Wq@keys^T * inv)
static constexpr size_t OFF_VL  = 93978624;          // [2][8][256][2] uint4 (vals regs)
static constexpr size_t OFF_KEY = 94109696;          // [2][192][128] f32
static constexpr size_t OFF_V32 = 94306304;          // [2][192][128] f32 vals
static constexpr size_t OFF_WQT = 94502912;          // [2][128][1024] f32 Wq^T
static constexpr size_t OFF_ENC = 95551488;          // [192][640] f32
static constexpr size_t OFF_RB  = 96043008;          // residual^T [512][80] f32
static constexpr size_t OFF_SEQ = 96206848;          // intermediate seq [512][80] f32
static constexpr size_t OFF_DYN = 96370688;
static constexpr size_t OFF_HAb = OFF_DYN + 0;       // ha [1024] f32
static constexpr size_t OFF_H1b = OFF_DYN + 4096;    // h1 [1024]
static constexpr size_t OFF_H2b = OFF_DYN + 8192;    // h2 [1024]
static constexpr size_t OFF_HDb = OFF_DYN + 12288;   // hd [1024]
static constexpr size_t OFF_YBb = OFF_DYN + 16384;   // y  [96] (80 used, pad 0)
static constexpr size_t OFF_SCb = OFF_DYN + 16896;   // scores [192]
static constexpr size_t OFF_CXb = OFF_DYN + 17920;   // ctx [128]
static constexpr size_t OFF_CTq = OFF_DYN + 18432;   // counters [7][8][32] int
static constexpr size_t DYN_BYTES = 18432 + 7168;
static constexpr size_t NEEDED = OFF_DYN + DYN_BYTES;

// phase indices
#define PA 0
#define PS 1
#define PX 2
#define P1 3
#define P2 4
#define PD 5
#define PF 6

// ---------------- device helpers ----------------
__device__ __forceinline__ float aldx(const float* p){ return __hip_atomic_load(p, __ATOMIC_RELAXED, AG); }
__device__ __forceinline__ void  astx(float* p, float v){ __hip_atomic_store(p, v, __ATOMIC_RELAXED, AG); }
__device__ __forceinline__ ull   aldx8(const ull* p){ return __hip_atomic_load(p, __ATOMIC_RELAXED, AG); }
__device__ __forceinline__ int   ldi(const int* p){ return __hip_atomic_load(p, __ATOMIC_RELAXED, AG); }

__device__ __forceinline__ float dot8(uint4 w, const float* v){
  float4 a = *(const float4*)v;
  float4 b = *(const float4*)(v+4);
  float s;
  s = __uint_as_float(w.x << 16) * a.x;
  s = fmaf(__uint_as_float(w.x & 0xffff0000u), a.y, s);
  s = fmaf(__uint_as_float(w.y << 16),         a.z, s);
  s = fmaf(__uint_as_float(w.y & 0xffff0000u), a.w, s);
  s = fmaf(__uint_as_float(w.z << 16),         b.x, s);
  s = fmaf(__uint_as_float(w.z & 0xffff0000u), b.y, s);
  s = fmaf(__uint_as_float(w.w << 16),         b.z, s);
  s = fmaf(__uint_as_float(w.w & 0xffff0000u), b.w, s);
  return s;
}
__device__ __forceinline__ float dot4(uint2 w, const float* v){
  float4 a = *(const float4*)v;
  float s;
  s = __uint_as_float(w.x << 16) * a.x;
  s = fmaf(__uint_as_float(w.x & 0xffff0000u), a.y, s);
  s = fmaf(__uint_as_float(w.y << 16),         a.z, s);
  s = fmaf(__uint_as_float(w.y & 0xffff0000u), a.w, s);
  return s;
}
__device__ __forceinline__ float sigf(float x){ return 1.f/(1.f+__expf(-x)); }
__device__ __forceinline__ float tanhf_(float x){
  x = fminf(12.f, fmaxf(-12.f, x));
  float t = __expf(2.f*x);
  return (t-1.f)/(t+1.f);
}

// ---------------- prep kernels ----------------
__global__ void k_init(float* z, int n){ int i = blockIdx.x*256 + threadIdx.x; if (i<n) z[i]=0.f; }

__global__ void k_rbuf(const float* res, float* rb){
  int i = blockIdx.x*256 + threadIdx.x; if (i >= 512*80) return;
  int t = i/80, m = i - t*80;
  rb[i] = res[m*512 + t];
}

__global__ void k_enc(const float* emb, const float* spk, const int* text, float* enc){
  int i = blockIdx.x*256 + threadIdx.x; if (i >= 192*640) return;
  int s = i/640, e = i - s*640;
  enc[i] = (e < 512) ? emb[(size_t)text[s]*512 + e] : spk[e-512];
}

__global__ void k_keysvals(const float* enc, const float* Wk, const float* Wv,
                           float* keys, float* vals32){
  int i = blockIdx.x*256 + threadIdx.x; if (i >= 2*192*128) return;
  int f = i/(192*128); int r = i - f*192*128; int s = r/128, a = r - s*128;
  float ka=0.f, va=0.f;
  for (int e=0;e<640;++e){
    float x = enc[s*640+e];
    ka = fmaf(x, Wk[((size_t)f*640+e)*128+a], ka);
    va = fmaf(x, Wv[((size_t)f*640+e)*128+a], va);
  }
  keys[((size_t)f*192+s)*128+a] = ka;
  vals32[((size_t)f*192+s)*128+a] = va;
}

__global__ void k_wqT(const float* Wq, float* WqT){
  int i = blockIdx.x*256 + threadIdx.x; if (i >= 2*128*1024) return;
  int f = i/(128*1024); int r = i - f*128*1024; int a = r/1024, h = r - a*1024;
  WqT[i] = Wq[((size_t)f*1024+h)*128+a];
}

__global__ void k_wqk2(const float* WqT, const float* keys, uint2* dst){
  int b = blockIdx.x; int f = b/192, s = b - f*192;
  int t = threadIdx.x;
  float4 acc = {0.f,0.f,0.f,0.f};
  const float* kp = keys + ((size_t)f*192+s)*128;
  const float* wp = WqT + (size_t)f*128*1024 + t*4;
  for (int a=0;a<128;++a){
    float kk = kp[a];
    float4 w = *(const float4*)(wp + (size_t)a*1024);
    acc.x = fmaf(kk, w.x, acc.x); acc.y = fmaf(kk, w.y, acc.y);
    acc.z = fmaf(kk, w.z, acc.z); acc.w = fmaf(kk, w.w, acc.w);
  }
  const float inv = 0.08838834764831845f;
  __hip_bfloat16 b0 = __float2bfloat16(acc.x*inv), b1 = __float2bfloat16(acc.y*inv);
  __hip_bfloat16 b2 = __float2bfloat16(acc.z*inv), b3 = __float2bfloat16(acc.w*inv);
  uint2 o;
  o.x = (uint32_t)(*(uint16_t*)&b0) | ((uint32_t)(*(uint16_t*)&b1) << 16);
  o.y = (uint32_t)(*(uint16_t*)&b2) | ((uint32_t)(*(uint16_t*)&b3) << 16);
  dst[((size_t)f*192+s)*256 + t] = o;
}

__device__ __forceinline__ uint32_t pk2(float a, float b){
  __hip_bfloat16 x = __float2bfloat16(a), y = __float2bfloat16(b);
  return (uint32_t)(*(uint16_t*)&x) | ((uint32_t)(*(uint16_t*)&y) << 16);
}

__global__ void k_packV(const float* vals32, uint4* dst){
  int i = blockIdx.x*256 + threadIdx.x; if (i >= 2*8*256*2) return;
  int j = i & 1; int r = i >> 1;
  int t = r & 255; r >>= 8;
  int ab = r & 7; int f = r >> 3;
  int a = ab*16 + (t>>4);
  int s0 = (t&15)*8 + j*128;
  float v[8];
  for (int e=0;e<8;++e){ int s = s0+e; v[e] = (s<192) ? vals32[((size_t)f*192+s)*128+a] : 0.f; }
  uint4 o; o.x = pk2(v[0],v[1]); o.y = pk2(v[2],v[3]); o.z = pk2(v[4],v[5]); o.w = pk2(v[6],v[7]);
  dst[i] = o;
}

// att-LSTM regs: j=0 chunk covers [y(80)|pad48]; j=1..8 cover haPrev(1024)
__global__ void k_packA2(const float* Wih, const float* Whh, uint4* dst){
  int i = blockIdx.x*256 + threadIdx.x; if (i >= 2*256*256*9) return;
  int j = i % 9; int r = i / 9;
  int t = r & 255; r >>= 8;
  int b = r & 255; int f = r >> 8;
  int rs = t>>4, ks = t&15;
  int row = (rs>>2)*1024 + b*4 + (rs&3);
  float v[8];
  for (int e=0;e<8;++e){
    int c = ks*8 + e;
    if (j == 0) v[e] = (c < 80) ? Wih[((size_t)f*4096+row)*80 + c] : 0.f;
    else        v[e] = Whh[((size_t)f*4096+row)*1024 + (j-1)*128 + c];
  }
  uint4 o; o.x = pk2(v[0],v[1]); o.y = pk2(v[2],v[3]); o.z = pk2(v[4],v[5]); o.w = pk2(v[6],v[7]);
  dst[i] = o;
}

__global__ void k_pack1b(const float* Wih1, const float* Whh1, uint4* dst){
  int i = blockIdx.x*256 + threadIdx.x; if (i >= 2*256*16*273) return;
  int kc = i % 273; int r = i / 273;
  int rr = r & 15; r >>= 4;
  int b = r & 255; int f = r >> 8;
  int row = (rr>>2)*1024 + b*4 + (rr&3);
  int k0 = kc*8;
  float v[8];
  for (int e=0;e<8;++e){
    int k = k0+e; float x;
    if (k < 1024)      x = Wih1[((size_t)f*4096+row)*1152 + k];
    else if (k < 2048) x = Whh1[((size_t)f*4096+row)*1024 + (k-1024)];
    else if (k < 2176) x = Wih1[((size_t)f*4096+row)*1152 + 1024 + (k-2048)];
    else               x = 0.f;
    v[e] = x;
  }
  uint4 o; o.x = pk2(v[0],v[1]); o.y = pk2(v[2],v[3]); o.z = pk2(v[4],v[5]); o.w = pk2(v[6],v[7]);
  dst[i] = o;
}

__global__ void k_pack2b(const float* Wih2, const float* Whh2, uint4* dst){
  int i = blockIdx.x*256 + threadIdx.x; if (i >= 2*256*16*257) return;
  int kc = i % 257; int r = i / 257;
  int rr = r & 15; r >>= 4;
  int b = r & 255; int f = r >> 8;
  int row = (rr>>2)*1024 + b*4 + (rr&3);
  int k0 = kc*8;
  float v[8];
  for (int e=0;e<8;++e){
    int k = k0+e;
    v[e] = (k < 1024) ? Wih2[((size_t)f*4096+row)*1024 + k]
         : (k < 2048) ? Whh2[((size_t)f*4096+row)*1024 + (k-1024)] : 0.f;
  }
  uint4 o; o.x = pk2(v[0],v[1]); o.y = pk2(v[2],v[3]); o.z = pk2(v[4],v[5]); o.w = pk2(v[6],v[7]);
  dst[i] = o;
}

__global__ void k_packD2(const float* Wd, uint4* dst){
  __shared__ float tile[64][65];
  int b = blockIdx.x; int f = b >> 8; int rem = b & 255;
  int ot = rem >> 4, ct = rem & 15;
  int tid = threadIdx.x;
  for (int i = tid; i < 4096; i += 256){
    int rc = i >> 6, oc = i & 63;
    tile[rc][oc] = Wd[((size_t)f*1024 + ct*64 + rc)*1024 + ot*64 + oc];
  }
  __syncthreads();
  for (int w = 0; w < 2; ++w){
    int idx = w*256 + tid;
    int op = idx >> 3, cc = idx & 7;
    int k6 = (ct&7)*8 + cc, j = ct >> 3;
    int o = ot*64 + op;
    int b2 = o >> 2, r2 = o & 3;
    uint4 out;
    out.x = pk2(tile[cc*8+0][op], tile[cc*8+1][op]);
    out.y = pk2(tile[cc*8+2][op], tile[cc*8+3][op]);
    out.z = pk2(tile[cc*8+4][op], tile[cc*8+5][op]);
    out.w = pk2(tile[cc*8+6][op], tile[cc*8+7][op]);
    dst[((((size_t)f*256 + b2)*256) + r2*64 + k6)*2 + j] = out;
  }
}

__global__ void k_packO2(const float* Wo, uint2* dst){
  int i = blockIdx.x*256 + threadIdx.x; if (i >= 2*80*256) return;
  int t = i & 255; int r = i >> 8;
  int m = r % 80; int f = r / 80;
  for (int j = 0; j < 2; ++j){
    int row = m + j*80;
    float v[4];
    for (int e=0;e<4;++e) v[e] = Wo[((size_t)f*1024 + t*4+e)*160 + row];
    uint2 o; o.x = pk2(v[0],v[1]); o.y = pk2(v[2],v[3]);
    dst[(size_t)i*2 + j] = o;
  }
}

// ---------------- main persistent kernel (one flow) ----------------
__launch_bounds__(256)
__global__ void k_flow3(uint8_t* ws, int fl, int rev, int out_mode,
    const float* b_att_all, const float* b1_all, const float* b2_all,
    const float* bd_all, const float* bo_all,
    const float* xsrc, float* ydst)
{
  const int tid = threadIdx.x, bid = blockIdx.x;
  const int rs = tid >> 4, ks = tid & 15;   // 16 rows x 16 k-slices
  const int wid = tid >> 6;

  float* habuf = (float*)(ws + OFF_HAb);
  float* h1buf = (float*)(ws + OFF_H1b);
  float* h2buf = (float*)(ws + OFF_H2b);
  float* hdbuf = (float*)(ws + OFF_HDb);
  float* ybuf  = (float*)(ws + OFF_YBb);
  float* scb   = (float*)(ws + OFF_SCb);
  float* cxbuf = (float*)(ws + OFF_CXb);
  int*   ctrs  = (int*)(ws + OFF_CTq);

  __shared__ __align__(16) ushort W1s[16*2184];
  __shared__ __align__(16) ushort W2s[16*2056];
  __shared__ __align__(16) float haPrevS[1024];
  __shared__ __align__(16) float S2[1024];   // h1prev -> h1new -> hd
  __shared__ __align__(16) float S3[1024];   // h2prev -> h2new
  __shared__ __align__(16) float yS[128];
  __shared__ __align__(16) float ctxS[128];
  __shared__ __align__(16) float att_s[256];
  __shared__ float zred[32];
  __shared__ float cst[3][4];
  __shared__ float bAs[16], b1s[16], b2s[16], bds[4], bos[2];

  const size_t fb = (size_t)fl*256 + bid;

  // ---- prologue: weights to LDS / regs ----
  { const uint4* src = (const uint4*)((const ushort*)(ws + OFF_W1) + fb*16*2184);
    uint4* dst = (uint4*)W1s;
    for (int i = tid; i < 4368; i += 256) dst[i] = src[i]; }
  { const uint4* src = (const uint4*)((const ushort*)(ws + OFF_W2) + fb*16*2056);
    uint4* dst = (uint4*)W2s;
    for (int i = tid; i < 4112; i += 256) dst[i] = src[i]; }
  uint4 wa[9];
  { const uint4* g = (const uint4*)(ws + OFF_WA) + (fb*256 + tid)*9;
    #pragma unroll
    for (int j = 0; j < 9; ++j) wa[j] = g[j]; }
  uint4 wd[2];
  { const uint4* g = (const uint4*)(ws + OFF_WD) + (fb*256 + tid)*2;
    wd[0] = g[0]; wd[1] = g[1]; }
  uint2 wqk = {0,0};
  if (bid < 192) wqk = ((const uint2*)(ws + OFF_WQ))[((size_t)fl*192 + bid)*256 + tid];
  uint4 vr0 = {0,0,0,0}, vr1 = {0,0,0,0};
  if (bid >= 248){ const uint4* g = (const uint4*)(ws + OFF_VL) + (((size_t)fl*8 + (bid-248))*256 + tid)*2;
    vr0 = g[0]; vr1 = g[1]; }
  uint2 wo0 = {0,0}, wo1 = {0,0};
  if (bid < 80){ const uint2* g = (const uint2*)(ws + OFF_WO) + (((size_t)fl*80 + bid)*256 + tid)*2;
    wo0 = g[0]; wo1 = g[1]; }
  if (tid < 16){
    int g = tid >> 2, uu = tid & 3;
    bAs[tid] = b_att_all[fl*4096 + g*1024 + bid*4 + uu];
    b1s[tid] = b1_all  [fl*4096 + g*1024 + bid*4 + uu];
    b2s[tid] = b2_all  [fl*4096 + g*1024 + bid*4 + uu];
  }
  if (tid < 4)  bds[tid] = bd_all[fl*1024 + bid*4 + tid];
  if (tid < 2 && bid < 80) bos[tid] = bo_all[fl*160 + tid*80 + bid];
  if (tid < 12) ((float*)cst)[tid] = 0.f;
  for (int i = tid; i < 1024; i += 256) haPrevS[i] = 0.f;
  __syncthreads();

  auto ADD = [&](int ph){
    __syncthreads();   // drains all threads' stores (compiler waitcnt before s_barrier)
    if (tid == 0) __hip_atomic_fetch_add(ctrs + ph*256 + (bid&7)*32, 1, __ATOMIC_RELEASE, AG);
  };
  auto POLL = [&](int ph, int tgt){
    if (tid < 64){
      const int* base = ctrs + ph*256;
      for(;;){
        int ok = (tid < 8) ? (ldi(base + tid*32) >= tgt) : 1;
        if (__all(ok)) break;
        __builtin_amdgcn_s_sleep(1);
      }
    }
    __syncthreads();
  };

  const uint4* w1row = (const uint4*)(W1s) + (size_t)rs*273;
  const uint4* w2row = (const uint4*)(W2s) + (size_t)rs*257;

  for (int t = 0; t < 512; ++t) {
    const int col = rev ? (511 - t) : t;

    // ---- stage prev-state (y, h1prev, h2prev) ----
    if (tid < 64){ ull v = (tid < 48) ? aldx8((const ull*)ybuf + tid) : 0ull;
                   ((ull*)yS)[tid] = v; }
    { const ull* g = (const ull*)h1buf; ull* s = (ull*)S2;
      s[tid] = aldx8(g + tid); s[tid+256] = aldx8(g + tid + 256); }
    { const ull* g = (const ull*)h2buf; ull* s = (ull*)S3;
      s[tid] = aldx8(g + tid); s[tid+256] = aldx8(g + tid + 256); }
    __syncthreads();

    // ===== phase A: attention-LSTM (K: y(80)+pad | haPrev(1024)) =====
    {
      float acc = dot8(wa[0], yS + ks*8);
      #pragma unroll
      for (int j = 1; j < 9; ++j) acc += dot8(wa[j], haPrevS + (j-1)*128 + ks*8);
      acc += __shfl_xor(acc,1); acc += __shfl_xor(acc,2);
      acc += __shfl_xor(acc,4); acc += __shfl_xor(acc,8);
      if (ks == 0) zred[rs] = acc + bAs[rs];
    }
    __syncthreads();
    if (tid < 4) {
      float zi=zred[tid], zf=zred[4+tid], zg=zred[8+tid], zo=zred[12+tid];
      float c = sigf(zf)*cst[0][tid] + sigf(zi)*tanhf_(zg);
      float h = sigf(zo)*tanhf_(c);
      cst[0][tid] = c;
      astx(habuf + bid*4 + tid, h);
    }

    // ---- precompute halves that only need prev state ----
    float acc1 = 0.f, acc2 = 0.f;
    #pragma unroll
    for (int j = 8; j < 16; ++j) acc1 += dot8(w1row[j*16 + ks], S2 + (j-8)*128 + ks*8);
    #pragma unroll
    for (int j = 8; j < 16; ++j) acc2 += dot8(w2row[j*16 + ks], S3 + (j-8)*128 + ks*8);

    ADD(PA);
    POLL(PA, 32*(t+1));

    // ---- stage ha(t) into haPrevS (used by scores, C, and next-step A) ----
    { const ull* g = (const ull*)habuf; ull* s = (ull*)haPrevS;
      s[tid] = aldx8(g + tid); s[tid+256] = aldx8(g + tid + 256); }
    __syncthreads();

    // ===== scores (blocks 0..191): s_bid = wqk . ha =====
    if (bid < 192) {
      float sv = dot4(wqk, haPrevS + tid*4);
      #pragma unroll
      for (int d=1; d<64; d<<=1) sv += __shfl_xor(sv, d);
      if ((tid&63) == 0) zred[16+wid] = sv;
      __syncthreads();
      if (tid == 0) astx(scb + bid, zred[16]+zred[17]+zred[18]+zred[19]);
      ADD(PS);
    }

    // ===== LSTM1 ha-half (all blocks) =====
    #pragma unroll
    for (int j = 0; j < 8; ++j) acc1 += dot8(w1row[j*16 + ks], haPrevS + j*128 + ks*8);

    // ===== ctx blocks (248..255): softmax + ctx slice =====
    if (bid >= 248) {
      POLL(PS, 24*(t+1));
      if (tid < 96) ((ull*)att_s)[tid] = aldx8((const ull*)scb + tid);
      else if (tid < 128) { att_s[tid+64] = 0.f; att_s[tid+96] = 0.f; }
      __syncthreads();
      float v = (tid < 192) ? att_s[tid] : -3.0e38f;
      float m = v;
      #pragma unroll
      for (int d=1; d<64; d<<=1) m = fmaxf(m, __shfl_xor(m, d));
      if ((tid&63) == 0) zred[16+wid] = m;
      __syncthreads();
      float mx = fmaxf(fmaxf(zred[16],zred[17]), fmaxf(zred[18],zred[19]));
      float e = (tid < 192) ? __expf(v - mx) : 0.f;
      float sm = e;
      #pragma unroll
      for (int d=1; d<64; d<<=1) sm += __shfl_xor(sm, d);
      if ((tid&63) == 0) zred[20+wid] = sm;
      __syncthreads();
      float inv = 1.f / (zred[20]+zred[21]+zred[22]+zred[23]);
      att_s[tid] = e * inv;
      __syncthreads();
      {
        float acc = dot8(vr0, att_s + ks*8) + dot8(vr1, att_s + 128 + ks*8);
        acc += __shfl_xor(acc,1); acc += __shfl_xor(acc,2);
        acc += __shfl_xor(acc,4); acc += __shfl_xor(acc,8);
        if (ks == 0) astx(cxbuf + (bid-248)*16 + rs, acc);
      }
      ADD(PX);
    }

    // ===== all: wait ctx, LSTM1 tail =====
    POLL(PX, (t+1));
    if (tid < 64) ((ull*)ctxS)[tid] = aldx8((const ull*)cxbuf + tid);
    __syncthreads();
    {
      acc1 += dot8(w1row[256 + ks], ctxS + ks*8);
      acc1 += __shfl_xor(acc1,1); acc1 += __shfl_xor(acc1,2);
      acc1 += __shfl_xor(acc1,4); acc1 += __shfl_xor(acc1,8);
      if (ks == 0) zred[rs] = acc1 + b1s[rs];
    }
    __syncthreads();
    if (tid < 4) {
      float zi=zred[tid], zf=zred[4+tid], zg=zred[8+tid], zo=zred[12+tid];
      float c = sigf(zf)*cst[1][tid] + sigf(zi)*tanhf_(zg);
      float h = sigf(zo)*tanhf_(c);
      cst[1][tid] = c;
      astx(h1buf + bid*4 + tid, h);
    }
    ADD(P1);
    POLL(P1, 32*(t+1));

    // ===== LSTM2 tail: h1(t) half =====
    { const ull* g = (const ull*)h1buf; ull* s = (ull*)S2;
      s[tid] = aldx8(g + tid); s[tid+256] = aldx8(g + tid + 256); }
    __syncthreads();
    {
      #pragma unroll
      for (int j = 0; j < 8; ++j) acc2 += dot8(w2row[j*16 + ks], S2 + j*128 + ks*8);
      acc2 += __shfl_xor(acc2,1); acc2 += __shfl_xor(acc2,2);
      acc2 += __shfl_xor(acc2,4); acc2 += __shfl_xor(acc2,8);
      if (ks == 0) zred[rs] = acc2 + b2s[rs];
    }
    __syncthreads();
    if (tid < 4) {
      float zi=zred[tid], zf=zred[4+tid], zg=zred[8+tid], zo=zred[12+tid];
      float c = sigf(zf)*cst[2][tid] + sigf(zi)*tanhf_(zg);
      float h = sigf(zo)*tanhf_(c);
      cst[2][tid] = c;
      astx(h2buf + bid*4 + tid, h);
    }
    ADD(P2);
    POLL(P2, 32*(t+1));

    // ===== phase E: hd = tanh(h2@Wd + bd) =====
    { const ull* g = (const ull*)h2buf; ull* s = (ull*)S3;
      s[tid] = aldx8(g + tid); s[tid+256] = aldx8(g + tid + 256); }
    __syncthreads();
    {
      int r2 = tid >> 6, k6 = tid & 63;
      float acc = dot8(wd[0], S3 + k6*8) + dot8(wd[1], S3 + 512 + k6*8);
      #pragma unroll
      for (int d=1; d<64; d<<=1) acc += __shfl_xor(acc, d);
      if ((tid & 63) == 0) {
        float hd = tanhf_(acc + bds[r2]);
        astx(hdbuf + bid*4 + r2, hd);
      }
    }
    ADD(PD);
    POLL(PD, 32*(t+1));

    // ===== phase F: out = hd@Wo + bo ; coupling inverse =====
    if (bid < 80) {
      float x = xsrc[col*80 + bid];
      { const ull* g = (const ull*)hdbuf; ull* s = (ull*)S2;
        s[tid] = aldx8(g + tid); s[tid+256] = aldx8(g + tid + 256); }
      __syncthreads();
      float pb = dot4(wo0, S2 + tid*4);
      float pl = dot4(wo1, S2 + tid*4);
      #pragma unroll
      for (int d=1; d<64; d<<=1) { pb += __shfl_xor(pb, d); pl += __shfl_xor(pl, d); }
      if ((tid & 63) == 0) { zred[16+wid] = pb; zred[20+wid] = pl; }
      __syncthreads();
      if (tid == 0) {
        float bp = zred[16]+zred[17]+zred[18]+zred[19] + bos[0];
        float ls = zred[20]+zred[21]+zred[22]+zred[23] + bos[1];
        float y = (x - bp) * __expf(-ls);
        if (out_mode == 0) ydst[col*80 + bid] = y;
        else               ydst[bid*512 + col] = y;
        astx(ybuf + bid, y);
      }
      ADD(PF);
    }
    POLL(PF, 10*(t+1));
  }
}

// ---------------- launch ----------------
extern "C" void kernel_launch(void* const* d_in, const int* in_sizes, int n_in,
                              void* d_out, int out_size, void* d_ws, size_t ws_size,
                              hipStream_t stream) {
  if (ws_size < NEEDED) return;
  uint8_t* ws = (uint8_t*)d_ws;
  const float* residual = (const float*)d_in[0];
  const float* spk      = (const float*)d_in[1];
  const float* emb      = (const float*)d_in[2];
  const float* Wih_att  = (const float*)d_in[3];
  const float* Whh_att  = (const float*)d_in[4];
  const float* b_att    = (const float*)d_in[5];
  const float* Wq       = (const float*)d_in[6];
  const float* Wk       = (const float*)d_in[7];
  const float* Wv       = (const float*)d_in[8];
  const float* Wih1     = (const float*)d_in[9];
  const float* Whh1     = (const float*)d_in[10];
  const float* b1       = (const float*)d_in[11];
  const float* Wih2     = (const float*)d_in[12];
  const float* Whh2     = (const float*)d_in[13];
  const float* b2       = (const float*)d_in[14];
  const float* Wd       = (const float*)d_in[15];
  const float* bd       = (const float*)d_in[16];
  const float* Wo       = (const float*)d_in[17];
  const float* bo       = (const float*)d_in[18];
  const int*   text     = (const int*)d_in[21];

  dim3 B(256);
  k_rbuf<<<160, B, 0, stream>>>(residual, (float*)(ws+OFF_RB));
  k_enc<<<480, B, 0, stream>>>(emb, spk, text, (float*)(ws+OFF_ENC));
  k_keysvals<<<192, B, 0, stream>>>((const float*)(ws+OFF_ENC), Wk, Wv,
                                    (float*)(ws+OFF_KEY), (float*)(ws+OFF_V32));
  k_wqT<<<1024, B, 0, stream>>>(Wq, (float*)(ws+OFF_WQT));
  k_wqk2<<<384, B, 0, stream>>>((const float*)(ws+OFF_WQT), (const float*)(ws+OFF_KEY),
                                (uint2*)(ws+OFF_WQ));
  k_packV<<<32, B, 0, stream>>>((const float*)(ws+OFF_V32), (uint4*)(ws+OFF_VL));
  k_packA2<<<4608, B, 0, stream>>>(Wih_att, Whh_att, (uint4*)(ws+OFF_WA));
  k_pack1b<<<8736, B, 0, stream>>>(Wih1, Whh1, (uint4*)(ws+OFF_W1));
  k_pack2b<<<8224, B, 0, stream>>>(Wih2, Whh2, (uint4*)(ws+OFF_W2));
  k_packD2<<<512, B, 0, stream>>>(Wd, (uint4*)(ws+OFF_WD));
  k_packO2<<<160, B, 0, stream>>>(Wo, (uint2*)(ws+OFF_WO));

  // flow 1 (backward): rb -> seq
  k_init<<<25, B, 0, stream>>>((float*)(ws+OFF_DYN), (int)(DYN_BYTES/4));
  k_flow3<<<256, B, 0, stream>>>(ws, 1, 1, 0, b_att, b1, b2, bd, bo,
                                 (const float*)(ws+OFF_RB), (float*)(ws+OFF_SEQ));
  // flow 0 (forward): seq -> dout
  k_init<<<25, B, 0, stream>>>((float*)(ws+OFF_DYN), (int)(DYN_BYTES/4));
  k_flow3<<<256, B, 0, stream>>>(ws, 0, 0, 1, b_att, b1, b2, bd, bo,
                                 (const float*)(ws+OFF_SEQ), (float*)d_out);
}